// Round 5
// baseline (1126.209 us; speedup 1.0000x reference)
//
#include <hip/hip_runtime.h>
#include <hip/hip_bf16.h>

// ProteinLigandAttention: D=256, B=256, 3 iters.
// R5: eliminate WRITE amplification (R4: 173MB measured vs 126MB unique on
// QKV-R => 1.37x partial-line eviction amplification from scattered 2-B
// stores). All epilogues now bounce C through padded LDS and drain with
// contiguous 16B/lane stores (8 lanes = one full 128-B line per instr):
//  - gemm bf16 out (NBUF=1 and NBUF=3), gemm fp32 final out, attn O store.
// k-loop unchanged from R4 (reg-staged X + XOR swizzle, zero bank conflicts,
// W direct L2->reg, bf16-only state).

#define DD 256
#define NCPLX 256
#define NITER 3

using s8v = __attribute__((ext_vector_type(8))) short;   // 8 bf16 = 4 VGPR
using f4v = __attribute__((ext_vector_type(4))) float;   // MFMA C/D

__device__ __forceinline__ short f2bf(float f) {
    union { float f; unsigned u; } v; v.f = f;
    unsigned r = v.u + 0x7fffu + ((v.u >> 16) & 1u);   // RNE
    return (short)(r >> 16);
}
__device__ __forceinline__ float bf2f(short s) {
    union { unsigned u; float f; } v;
    v.u = ((unsigned)(unsigned short)s) << 16;
    return v.f;
}
__device__ __forceinline__ float4 ld4f(const float* p) { return *reinterpret_cast<const float4*>(p); }

// ---------- scope normalization (int32 vs int64) ----------
__global__ void conv_scope(const int* __restrict__ lig, const int* __restrict__ res,
                           int nA, int nR, int* __restrict__ ligN, int* __restrict__ resN)
{
    const int b = threadIdx.x;
    const bool l64 = (lig[2*(NCPLX-1)] + lig[2*(NCPLX-1)+1]) != nA;
    const bool r64 = (res[2*(NCPLX-1)] + res[2*(NCPLX-1)+1]) != nR;
    ligN[2*b]   = l64 ? lig[4*b]   : lig[2*b];
    ligN[2*b+1] = l64 ? lig[4*b+2] : lig[2*b+1];
    resN[2*b]   = r64 ? res[4*b]   : res[2*b];
    resN[2*b+1] = r64 ? res[4*b+2] : res[2*b+1];
}

__global__ void scales_k(const int* __restrict__ lig, const int* __restrict__ res,
                         float* __restrict__ sA, float* __restrict__ sR)
{
    int b = blockIdx.x, t = threadIdx.x;
    int a0 = lig[2*b], ac = lig[2*b+1];
    int r0 = res[2*b], rc = res[2*b+1];
    float va = 1.0f / (float)rc, vr = 1.0f / (float)ac;
    for (int i = t; i < ac; i += blockDim.x) sA[a0+i] = va;
    for (int i = t; i < rc; i += blockDim.x) sR[r0+i] = vr;
}

// ---------- one-time weight convert+transpose: Wt[n][k] bf16, 10 weights ----------
// Layout: 0=WQl 1=WKl 2=WVl 3=WOl 4=WQr 5=WKr 6=WVr 7=WOr 8=Wlig 9=Wres
__global__ __launch_bounds__(256) void wtrans(
    const float* w0, const float* w1, const float* w2, const float* w3,
    const float* w4, const float* w5, const float* w6, const float* w7,
    const float* w8, const float* w9, short* __restrict__ out)
{
    const float* W;
    switch (blockIdx.x) {
        case 0: W = w0; break; case 1: W = w1; break; case 2: W = w2; break;
        case 3: W = w3; break; case 4: W = w4; break; case 5: W = w5; break;
        case 6: W = w6; break; case 7: W = w7; break; case 8: W = w8; break;
        default: W = w9; break;
    }
    short* O = out + (size_t)blockIdx.x * 65536;
    const int tile = blockIdx.y;             // 64 tiles of 32x32
    const int tr = (tile >> 3) * 32, tc = (tile & 7) * 32;
    __shared__ short T[32 * 34];
    const int t = threadIdx.x;
#pragma unroll
    for (int i = 0; i < 4; ++i) {
        int idx = t + i * 256, r = idx >> 5, c = idx & 31;
        T[c * 34 + r] = f2bf(W[(size_t)(tr + r) * 256 + tc + c]);
    }
    __syncthreads();
#pragma unroll
    for (int i = 0; i < 4; ++i) {
        int idx = t + i * 256, nn = idx >> 5, kk = idx & 31;
        O[(size_t)(tc + nn) * 256 + tr + kk] = T[nn * 34 + kk];
    }
}

// ---------- unified bf16 MFMA GEMM ----------
// Y = [leaky](X @ Wt^T)[*scale][+resid(bf16)]; X fp32 or bf16.
// Wt: [NBUF*256 n][256 k] k-contiguous. 128x128 tile, 4 waves of 64x64.
// X staged to LDS (2 buffers, XOR chunk swizzle); W L2->registers (2-deep).
// NBUF=3: virtual N=768. Epilogue: LDS bounce -> full-line 16B/lane stores.
template <bool XF32, bool LEAKY, bool SCALE, bool RESID, bool WF32, bool WBF16, int NBUF>
__global__ __launch_bounds__(256, 3) void gemm_mfma(
    const void* __restrict__ Xv, const short* __restrict__ W,
    float* __restrict__ Yf, short* __restrict__ Yb, size_t bufstride,
    const short* __restrict__ residb, const float* __restrict__ rowscale, int n)
{
    __shared__ __align__(1024) short Xs[2][128 * 32];   // 2 x 8KB k-loop staging
    __shared__ __align__(1024) short Eb[4][32 * 72];    // 18KB epilogue bounce
    const int t = threadIdx.x, lane = t & 63, wave = t >> 6;
    const int wm = (wave & 1) * 64, wn = (wave >> 1) * 64;

    // XCD-aware bijective swizzle (m204): consecutive swizzled ids stay on
    // one XCD; x remains fastest, so all col-blocks of one row-tile share L2.
    const int nbx = gridDim.x;
    const int total = nbx * gridDim.y;
    const int lin = blockIdx.y * nbx + blockIdx.x;
    const int qq = total >> 3, rr = total & 7, cc = lin & 7, ss = lin >> 3;
    const int w = (cc < rr ? cc * (qq + 1) : rr * (qq + 1) + (cc - rr) * qq) + ss;
    const int bx = w % nbx, by = w / nbx;
    const int col0 = bx * 128, row0 = by * 128;
    const int l15 = lane & 15, lg = lane >> 4;
    const int rchunk = (lg ^ ((l15 >> 1) & 3)) * 8;     // swizzled read chunk (shorts)

    const float* Xf = (const float*)Xv;
    const short* Xb = (const short*)Xv;

    f4v acc[16];
#pragma unroll
    for (int i = 0; i < 16; ++i) acc[i] = (f4v){0.f, 0.f, 0.f, 0.f};

    s8v rw[2][4];       // W fragments, 2-deep prefetch, straight from L2
    s8v rxb[2][2];      // bf16 X prefetch regs
    float4 rxf[2][4];   // fp32 X prefetch regs

    auto wload = [&](int set, int k0) {
#pragma unroll
        for (int j = 0; j < 4; ++j)
            rw[set][j] = *(const s8v*)(W + (size_t)(col0 + wn + j*16 + l15) * 256 + k0 + lg * 8);
    };
    auto gld = [&](int set, int k0) {
        if constexpr (XF32) {
#pragma unroll
            for (int i = 0; i < 4; ++i) {
                int idx = t + i * 256, r = idx >> 3, kp = (idx & 7) * 4;
                int gr = row0 + r;
                float4 xv = make_float4(0.f, 0.f, 0.f, 0.f);
                if (gr < n) xv = ld4f(Xf + (size_t)gr * 256 + k0 + kp);
                rxf[set][i] = xv;
            }
        } else {
#pragma unroll
            for (int i = 0; i < 2; ++i) {
                int c = t + i * 256, r = c >> 2, kp = (c & 3) * 8;
                int gr = row0 + r;
                s8v xv = (s8v){0,0,0,0,0,0,0,0};
                if (gr < n) xv = *(const s8v*)(Xb + (size_t)gr * 256 + k0 + kp);
                rxb[set][i] = xv;
            }
        }
    };
    auto gst = [&](int set, int buf) {
        if constexpr (XF32) {
#pragma unroll
            for (int i = 0; i < 4; ++i) {
                int idx = t + i * 256, r = idx >> 3, kp = (idx & 7) * 4;
                int c = kp >> 3, sub = kp & 7;
                float4 xv = rxf[set][i];
                short4 s4;
                s4.x = f2bf(xv.x); s4.y = f2bf(xv.y); s4.z = f2bf(xv.z); s4.w = f2bf(xv.w);
                *(short4*)(&Xs[buf][r * 32 + (c ^ ((r >> 1) & 3)) * 8 + sub]) = s4;
            }
        } else {
#pragma unroll
            for (int i = 0; i < 2; ++i) {
                int c = t + i * 256, r = c >> 2, ch = c & 3;
                *(s8v*)(&Xs[buf][r * 32 + (ch ^ ((r >> 1) & 3)) * 8]) = rxb[set][i];
            }
        }
    };

    // prologue: tile0 -> LDS buf0, tile1 loads in flight, W sets 0/1
    gld(0, 0);
    gst(0, 0);
    gld(1, 32);
    wload(0, 0);
    wload(1, 32);
    __syncthreads();

#pragma unroll
    for (int kk = 0; kk < 8; ++kk) {
        const int cur = kk & 1;
        if (kk + 2 < 8) gld(cur, (kk + 2) * 32);        // set cur consumed last iter
        const short* Xbuf = Xs[cur];
        s8v af[4];
#pragma unroll
        for (int i = 0; i < 4; ++i)
            af[i] = *(const s8v*)(Xbuf + (wm + i*16 + l15) * 32 + rchunk);
#pragma unroll
        for (int i = 0; i < 4; ++i)
#pragma unroll
            for (int j = 0; j < 4; ++j)
                acc[i*4+j] = __builtin_amdgcn_mfma_f32_16x16x32_bf16(af[i], rw[cur][j], acc[i*4+j], 0, 0, 0);
        if (kk + 2 < 8) wload(cur, (kk + 2) * 32);
        __syncthreads();                                 // all waves done with buf[cur]
        if (kk + 1 < 8) {
            gst((kk + 1) & 1, (kk + 1) & 1);             // tile kk+1 -> other buffer
            __syncthreads();
        }
    }

    // ---- epilogue: act/scale/resid in regs -> LDS bounce -> 16B/lane stores
    const int buf3 = col0 >> 8;                  // NBUF=3: whole block in 1 buffer
    const int cin  = (col0 & 255) + wn;          // col base within buffer
    if (WBF16) {
        short* Ew = &Eb[wave][0];                // 32 rows x 64 cols, stride 72
#pragma unroll
        for (int p = 0; p < 2; ++p) {
#pragma unroll
            for (int i2 = 0; i2 < 2; ++i2) {
                const int i = p*2 + i2;
#pragma unroll
                for (int r = 0; r < 4; ++r) {
                    int gr = row0 + wm + i*16 + lg*4 + r;
                    float sc = SCALE ? ((gr < n) ? rowscale[gr] : 0.f) : 1.0f;
#pragma unroll
                    for (int j = 0; j < 4; ++j) {
                        float v = acc[i*4+j][r];
                        if (LEAKY) v = (v >= 0.f) ? v : 0.1f * v;
                        if (SCALE) v *= sc;
                        if (RESID && gr < n)
                            v += bf2f(residb[(size_t)gr * 256 + col0 + wn + j*16 + l15]);
                        Ew[(i2*16 + lg*4 + r) * 72 + j*16 + l15] = f2bf(v);
                    }
                }
            }
            __builtin_amdgcn_s_waitcnt(0xc07f);  // lgkmcnt(0): wave-local LDS RAW
#pragma unroll
            for (int q = 0; q < 4; ++q) {        // 32x64 = 256 16B chunks, 4/lane
                int c = q*64 + lane;
                int r32 = c >> 3, cc8 = c & 7;
                s8v v8 = *(const s8v*)(Ew + r32*72 + cc8*8);
                int gr = row0 + wm + p*32 + r32;
                if (gr < n) {
                    if (NBUF == 1)
                        *(s8v*)(Yb + (size_t)gr*256 + col0 + wn + cc8*8) = v8;
                    else
                        *(s8v*)(Yb + (size_t)buf3*bufstride + (size_t)gr*256 + cin + cc8*8) = v8;
                }
            }
            __builtin_amdgcn_s_waitcnt(0xc07f);  // drain reads before region reuse
        }
    }
    if (WF32) {
        float* Ef = (float*)&Eb[wave][0];        // 16 rows x 64 f32, stride 72
#pragma unroll
        for (int i = 0; i < 4; ++i) {
#pragma unroll
            for (int r = 0; r < 4; ++r) {
                int gr = row0 + wm + i*16 + lg*4 + r;
                float sc = SCALE ? ((gr < n) ? rowscale[gr] : 0.f) : 1.0f;
#pragma unroll
                for (int j = 0; j < 4; ++j) {
                    float v = acc[i*4+j][r];
                    if (LEAKY) v = (v >= 0.f) ? v : 0.1f * v;
                    if (SCALE) v *= sc;
                    if (RESID && gr < n)
                        v += bf2f(residb[(size_t)gr * 256 + col0 + wn + j*16 + l15]);
                    Ef[(lg*4 + r) * 72 + j*16 + l15] = v;
                }
            }
            __builtin_amdgcn_s_waitcnt(0xc07f);
#pragma unroll
            for (int q = 0; q < 4; ++q) {        // 16x64 f32 = 256 16B chunks
                int c = q*64 + lane;
                int r16 = c >> 4, cc4 = c & 15;
                float4 v4 = *(const float4*)(Ef + r16*72 + cc4*4);
                int gr = row0 + wm + i*16 + r16;
                if (gr < n) *(float4*)(Yf + (size_t)gr*256 + col0 + wn + cc4*4) = v4;
            }
            __builtin_amdgcn_s_waitcnt(0xc07f);
        }
    }
}

// ---------- MFMA sigmoid attention: O = sum_tiles sigmoid(Q Kt^T) Vt ----------
__global__ __launch_bounds__(256, 2) void attn_mfma(
    const short* __restrict__ Qb, const short* __restrict__ Kb, const short* __restrict__ Vb,
    short* __restrict__ Ob, const int* __restrict__ qs, const int* __restrict__ ks)
{
    __shared__ short Kl[32 * 264];
    __shared__ short Vt[256 * 40];
    __shared__ short Ss[4][16 * 40];
    __shared__ short Oe[4][16 * 264];              // epilogue bounce, stride 264
    const int b = blockIdx.x;
    const int q0 = qs[2*b], qc = qs[2*b+1];
    const int k0 = ks[2*b], kc = ks[2*b+1];
    if ((int)blockIdx.y * 64 >= qc) return;           // block-uniform exit
    const int t = threadIdx.x, lane = t & 63, wave = t >> 6;
    const int l15 = lane & 15, lg = lane >> 4;
    const int qtile = blockIdx.y * 4 + wave;
    const bool valid = qtile * 16 < qc;

    s8v qf[8];
    {
        int qr = qtile * 16 + l15;
        if (qr >= qc) qr = qc - 1;                     // clamp (results discarded)
        const short* qp = Qb + (size_t)(q0 + qr) * 256 + lg * 8;
#pragma unroll
        for (int s = 0; s < 8; ++s) qf[s] = *(const s8v*)(qp + s * 32);
    }
    f4v o[16];
#pragma unroll
    for (int i = 0; i < 16; ++i) o[i] = (f4v){0.f, 0.f, 0.f, 0.f};

    const int nkt = (kc + 31) >> 5;
    for (int kt = 0; kt < nkt; ++kt) {
        __syncthreads();
#pragma unroll
        for (int i = 0; i < 4; ++i) {
            int c = t + i * 256;                       // 0..1023
            int key = c >> 5, d0 = (c & 31) * 8;
            int gk = kt * 32 + key;
            s8v kv = (s8v){0,0,0,0,0,0,0,0}, vv = kv;
            if (gk < kc) {
                kv = *(const s8v*)(Kb + (size_t)(k0 + gk) * 256 + d0);
                vv = *(const s8v*)(Vb + (size_t)(k0 + gk) * 256 + d0);
            }
            *(s8v*)(Kl + key * 264 + d0) = kv;
#pragma unroll
            for (int j = 0; j < 8; ++j) {
                int d = d0 + j;
                int kcol = key ^ (((d >> 3) & 3) << 3);   // XOR-8 swizzle
                Vt[d * 40 + kcol] = vv[j];
            }
        }
        __syncthreads();
        if (valid) {
#pragma unroll
            for (int nt = 0; nt < 2; ++nt) {
                f4v s = (f4v){0.f, 0.f, 0.f, 0.f};
#pragma unroll
                for (int ss = 0; ss < 8; ++ss) {
                    s8v kb = *(const s8v*)(Kl + (nt*16 + l15) * 264 + ss * 32 + lg * 8);
                    s = __builtin_amdgcn_mfma_f32_16x16x32_bf16(qf[ss], kb, s, 0, 0, 0);
                }
#pragma unroll
                for (int r = 0; r < 4; ++r) {
                    float sv = 1.0f / (1.0f + __expf(-s[r]));
                    Ss[wave][(lg*4 + r) * 40 + nt*16 + l15] = f2bf(sv);
                }
            }
            __builtin_amdgcn_s_waitcnt(0xc07f);        // lgkmcnt(0): S write->read
            s8v sa = *(const s8v*)(&Ss[wave][0] + l15 * 40 + lg * 8);
#pragma unroll
            for (int nt = 0; nt < 16; ++nt) {
                int rowb = nt * 16 + l15;
                s8v vb = *(const s8v*)(Vt + rowb * 40 + (lg ^ ((rowb >> 3) & 3)) * 8);
                o[nt] = __builtin_amdgcn_mfma_f32_16x16x32_bf16(sa, vb, o[nt], 0, 0, 0);
            }
        }
    }
    if (valid) {
        // LDS bounce -> contiguous 16B/lane stores (full 128B lines)
        short* Ow = &Oe[wave][0];                      // 16 rows x 256 cols
#pragma unroll
        for (int nt = 0; nt < 16; ++nt)
#pragma unroll
            for (int r = 0; r < 4; ++r)
                Ow[(lg*4 + r) * 264 + nt*16 + l15] = f2bf(o[nt][r]);
        __builtin_amdgcn_s_waitcnt(0xc07f);
#pragma unroll
        for (int q = 0; q < 8; ++q) {                  // 16x256 = 512 16B chunks
            int c = q*64 + lane;
            int r16 = c >> 5, cc = c & 31;
            s8v v8 = *(const s8v*)(Ow + r16*264 + cc*8);
            int qr = qtile*16 + r16;
            if (qr < qc) *(s8v*)(Ob + (size_t)(q0 + qr)*256 + cc*8) = v8;
        }
    }
}

extern "C" void kernel_launch(void* const* d_in, const int* in_sizes, int n_in,
                              void* d_out, int out_size, void* d_ws, size_t ws_size,
                              hipStream_t stream)
{
    const float* fatoms = (const float*)d_in[0];
    const float* fres   = (const float*)d_in[1];
    const int* lig_raw  = (const int*)d_in[12];
    const int* res_raw  = (const int*)d_in[13];
    const int nA = in_sizes[0] / DD;
    const int nR = in_sizes[1] / DD;
    (void)n_in; (void)out_size; (void)ws_size;

    char* p = (char*)d_ws;
    auto carve = [&](size_t bytes) -> void* {
        void* r = (void*)p;
        p += (bytes + 255) & ~(size_t)255;
        return r;
    };
    short* Ab = (short*)carve((size_t)nA * DD * 2);   // bf16 state
    short* Rb = (short*)carve((size_t)nR * DD * 2);
    short* AQ = (short*)carve((size_t)nA * DD * 2);   // AQ,AK,AV contiguous (QKV decode)
    short* AK = (short*)carve((size_t)nA * DD * 2);
    short* AV = (short*)carve((size_t)nA * DD * 2);
    short* RQ = (short*)carve((size_t)nR * DD * 2);   // RQ,RK,RV contiguous
    short* RK = (short*)carve((size_t)nR * DD * 2);
    short* RV = (short*)carve((size_t)nR * DD * 2);
    float* sA = (float*)carve((size_t)nA * 4);
    float* sR = (float*)carve((size_t)nR * 4);
    int* ligN = (int*)carve(NCPLX * 2 * 4);
    int* resN = (int*)carve(NCPLX * 2 * 4);
    short* Wt = (short*)carve((size_t)10 * 65536 * 2); // 10 transposed bf16 weights
    (void)AK; (void)AV; (void)RK; (void)RV;

    const short* WqkvL = Wt + 0*65536;   // QKl,WKl,WVl contiguous (N=768)
    const short* WOlT  = Wt + 3*65536;
    const short* WqkvR = Wt + 4*65536;   // QKr,WKr,WVr contiguous
    const short* WOrT  = Wt + 7*65536;
    const short* WligT = Wt + 8*65536;
    const short* WresT = Wt + 9*65536;

    float* out = (float*)d_out;
    const dim3 blk(256);
    const int gA = (nA + 127) / 128, gR = (nR + 127) / 128;
    const size_t bsA = (size_t)nA * DD, bsR = (size_t)nR * DD;

    conv_scope<<<1, NCPLX, 0, stream>>>(lig_raw, res_raw, nA, nR, ligN, resN);
    scales_k<<<NCPLX, 256, 0, stream>>>(ligN, resN, sA, sR);
    wtrans<<<dim3(10, 64), blk, 0, stream>>>(
        (const float*)d_in[4], (const float*)d_in[5], (const float*)d_in[6], (const float*)d_in[7],
        (const float*)d_in[8], (const float*)d_in[9], (const float*)d_in[10], (const float*)d_in[11],
        (const float*)d_in[2], (const float*)d_in[3], Wt);

    // input transforms: bf16 state only
    gemm_mfma<true,true,false,false,false,true,1><<<dim3(2, gA), blk, 0, stream>>>(
        fatoms, WligT, nullptr, Ab, 0, nullptr, nullptr, nA);
    gemm_mfma<true,true,false,false,false,true,1><<<dim3(2, gR), blk, 0, stream>>>(
        fres, WresT, nullptr, Rb, 0, nullptr, nullptr, nR);

    for (int it = 0; it < NITER; ++it) {
        // fused QKV projections: one N=768 GEMM per side
        gemm_mfma<false,false,false,false,false,true,3><<<dim3(6, gA), blk, 0, stream>>>(
            Ab, WqkvL, nullptr, AQ, bsA, nullptr, nullptr, nA);
        gemm_mfma<false,false,false,false,false,true,3><<<dim3(6, gR), blk, 0, stream>>>(
            Rb, WqkvR, nullptr, RQ, bsR, nullptr, nullptr, nR);

        attn_mfma<<<dim3(NCPLX, 1), blk, 0, stream>>>(AQ, RK, RV, AQ, ligN, resN);
        attn_mfma<<<dim3(NCPLX, 8), blk, 0, stream>>>(RQ, AK, AV, RQ, resN, ligN);

        if (it < NITER - 1) {
            // state update in bf16: read resid Ab/Rb, write Ab/Rb (same-thread RMW, safe)
            gemm_mfma<false,true,true,true,false,true,1><<<dim3(2, gA), blk, 0, stream>>>(
                AQ, WOlT, nullptr, Ab, 0, Ab, sA, nA);
            gemm_mfma<false,true,true,true,false,true,1><<<dim3(2, gR), blk, 0, stream>>>(
                RQ, WOrT, nullptr, Rb, 0, Rb, sR, nR);
        } else {
            gemm_mfma<false,true,true,true,true,false,1><<<dim3(2, gA), blk, 0, stream>>>(
                AQ, WOlT, out, nullptr, 0, Ab, sA, nA);
            gemm_mfma<false,true,true,true,true,false,1><<<dim3(2, gR), blk, 0, stream>>>(
                RQ, WOrT, out + bsA, nullptr, 0, Rb, sR, nR);
        }
    }
}

// Round 6
// 793.037 us; speedup vs baseline: 1.4201x; 1.4201x over previous
//
#include <hip/hip_runtime.h>
#include <hip/hip_bf16.h>

// ProteinLigandAttention: D=256, B=256, 3 iters.
// R6 = R1's proven structure VERBATIM (X and W staged through 40KB LDS,
// 2-deep register prefetch, plain __syncthreads, XCD bijective swizzle —
// QKV-R measured 80us) + ONE orthogonal change: bf16-only state.
// fp32 A/R arrays eliminated (downstream QKV consumed the bf16 shadow
// anyway; bf16 resid-add measured absmax 0.0625 vs 0.146 threshold).
// Per-iter traffic: WO-R 252->126MB, xform-R 213->126MB.
// Lesson ledger: every k-loop deviation from this structure (W-direct-to-reg
// R4: 116us, DMA+sched_barrier R3: 103us, LDS bounce R5) regressed.

#define DD 256
#define NCPLX 256
#define NITER 3

using s8v = __attribute__((ext_vector_type(8))) short;   // 8 bf16 = 4 VGPR
using f4v = __attribute__((ext_vector_type(4))) float;   // MFMA C/D

__device__ __forceinline__ short f2bf(float f) {
    union { float f; unsigned u; } v; v.f = f;
    unsigned r = v.u + 0x7fffu + ((v.u >> 16) & 1u);   // RNE
    return (short)(r >> 16);
}
__device__ __forceinline__ float bf2f(short s) {
    union { unsigned u; float f; } v;
    v.u = ((unsigned)(unsigned short)s) << 16;
    return v.f;
}
__device__ __forceinline__ float4 ld4f(const float* p) { return *reinterpret_cast<const float4*>(p); }

// ---------- scope normalization (int32 vs int64) ----------
__global__ void conv_scope(const int* __restrict__ lig, const int* __restrict__ res,
                           int nA, int nR, int* __restrict__ ligN, int* __restrict__ resN)
{
    const int b = threadIdx.x;
    const bool l64 = (lig[2*(NCPLX-1)] + lig[2*(NCPLX-1)+1]) != nA;
    const bool r64 = (res[2*(NCPLX-1)] + res[2*(NCPLX-1)+1]) != nR;
    ligN[2*b]   = l64 ? lig[4*b]   : lig[2*b];
    ligN[2*b+1] = l64 ? lig[4*b+2] : lig[2*b+1];
    resN[2*b]   = r64 ? res[4*b]   : res[2*b];
    resN[2*b+1] = r64 ? res[4*b+2] : res[2*b+1];
}

__global__ void scales_k(const int* __restrict__ lig, const int* __restrict__ res,
                         float* __restrict__ sA, float* __restrict__ sR)
{
    int b = blockIdx.x, t = threadIdx.x;
    int a0 = lig[2*b], ac = lig[2*b+1];
    int r0 = res[2*b], rc = res[2*b+1];
    float va = 1.0f / (float)rc, vr = 1.0f / (float)ac;
    for (int i = t; i < ac; i += blockDim.x) sA[a0+i] = va;
    for (int i = t; i < rc; i += blockDim.x) sR[r0+i] = vr;
}

// ---------- one-time weight convert+transpose: Wt[n][k] bf16, 10 weights ----------
// Layout: 0=WQl 1=WKl 2=WVl 3=WOl 4=WQr 5=WKr 6=WVr 7=WOr 8=Wlig 9=Wres
__global__ __launch_bounds__(256) void wtrans(
    const float* w0, const float* w1, const float* w2, const float* w3,
    const float* w4, const float* w5, const float* w6, const float* w7,
    const float* w8, const float* w9, short* __restrict__ out)
{
    const float* W;
    switch (blockIdx.x) {
        case 0: W = w0; break; case 1: W = w1; break; case 2: W = w2; break;
        case 3: W = w3; break; case 4: W = w4; break; case 5: W = w5; break;
        case 6: W = w6; break; case 7: W = w7; break; case 8: W = w8; break;
        default: W = w9; break;
    }
    short* O = out + (size_t)blockIdx.x * 65536;
    const int tile = blockIdx.y;             // 64 tiles of 32x32
    const int tr = (tile >> 3) * 32, tc = (tile & 7) * 32;
    __shared__ short T[32 * 34];
    const int t = threadIdx.x;
#pragma unroll
    for (int i = 0; i < 4; ++i) {
        int idx = t + i * 256, r = idx >> 5, c = idx & 31;
        T[c * 34 + r] = f2bf(W[(size_t)(tr + r) * 256 + tc + c]);
    }
    __syncthreads();
#pragma unroll
    for (int i = 0; i < 4; ++i) {
        int idx = t + i * 256, nn = idx >> 5, kk = idx & 31;
        O[(size_t)(tc + nn) * 256 + tr + kk] = T[nn * 34 + kk];
    }
}

// ---------- unified bf16 MFMA GEMM (R1 structure) ----------
// Y = [leaky](X @ Wt^T)[*scale][+resid(bf16)]; X fp32 (converted in staging)
// or bf16. Wt: [NBUF*256 n][256 k] k-contiguous. 128x128 tile, 4 waves of
// 64x64. LDS stride 40 shorts. NBUF=3: virtual N=768, out buffer = gc>>8.
// Pipeline: double-buffered LDS + 2-deep register prefetch; XCD swizzle.

#define GEMM_GLD(SET, K0)                                                      \
    do {                                                                       \
        if constexpr (XF32) {                                                  \
            _Pragma("unroll")                                                  \
            for (int _i = 0; _i < 4; ++_i) {                                   \
                int _idx = t + _i * 256, _r = _idx >> 3, _kp = (_idx & 7) * 4; \
                int _gr = row0 + _r;                                           \
                float4 _xv = make_float4(0.f, 0.f, 0.f, 0.f);                  \
                if (_gr < n) _xv = ld4f(Xf + (size_t)_gr * 256 + (K0) + _kp);  \
                rxf[SET][_i] = _xv;                                            \
            }                                                                  \
        } else {                                                               \
            _Pragma("unroll")                                                  \
            for (int _i = 0; _i < 2; ++_i) {                                   \
                int _c = t + _i * 256, _r = _c >> 2, _kp = (_c & 3) * 8;       \
                int _gr = row0 + _r;                                           \
                s8v _xv = (s8v){0, 0, 0, 0, 0, 0, 0, 0};                       \
                if (_gr < n) _xv = *(const s8v*)(Xb + (size_t)_gr * 256 + (K0) + _kp); \
                rxb[SET][_i] = _xv;                                            \
            }                                                                  \
        }                                                                      \
        _Pragma("unroll")                                                      \
        for (int _i = 0; _i < 2; ++_i) {                                       \
            int _c = t + _i * 256, _r = _c >> 2, _kp = (_c & 3) * 8;           \
            rw[SET][_i] = *(const s8v*)(W + (size_t)(col0 + _r) * 256 + (K0) + _kp); \
        }                                                                      \
    } while (0)

#define GEMM_GST(SET, BUF)                                                     \
    do {                                                                       \
        if constexpr (XF32) {                                                  \
            _Pragma("unroll")                                                  \
            for (int _i = 0; _i < 4; ++_i) {                                   \
                int _idx = t + _i * 256, _r = _idx >> 3, _kp = (_idx & 7) * 4; \
                float4 _xv = rxf[SET][_i];                                     \
                short4 _s4;                                                    \
                _s4.x = f2bf(_xv.x); _s4.y = f2bf(_xv.y);                      \
                _s4.z = f2bf(_xv.z); _s4.w = f2bf(_xv.w);                      \
                *(short4*)(Xs[BUF] + _r * 40 + _kp) = _s4;                     \
            }                                                                  \
        } else {                                                               \
            _Pragma("unroll")                                                  \
            for (int _i = 0; _i < 2; ++_i) {                                   \
                int _c = t + _i * 256, _r = _c >> 2, _kp = (_c & 3) * 8;       \
                *(s8v*)(Xs[BUF] + _r * 40 + _kp) = rxb[SET][_i];               \
            }                                                                  \
        }                                                                      \
        _Pragma("unroll")                                                      \
        for (int _i = 0; _i < 2; ++_i) {                                       \
            int _c = t + _i * 256, _r = _c >> 2, _kp = (_c & 3) * 8;           \
            *(s8v*)(Ws[BUF] + _r * 40 + _kp) = rw[SET][_i];                    \
        }                                                                      \
    } while (0)

template <bool XF32, bool LEAKY, bool SCALE, bool RESID, bool WF32, bool WBF16, int NBUF>
__global__ __launch_bounds__(256, 2) void gemm_mfma(
    const void* __restrict__ Xv, const short* __restrict__ W,
    float* __restrict__ Yf, short* __restrict__ Yb, size_t bufstride,
    const short* __restrict__ residb, const float* __restrict__ rowscale, int n)
{
    __shared__ short Xs[2][128 * 40];
    __shared__ short Ws[2][128 * 40];
    const int t = threadIdx.x, lane = t & 63, wave = t >> 6;
    const int wm = (wave & 1) * 64, wn = (wave >> 1) * 64;

    // XCD-aware bijective swizzle (m204): consecutive swizzled ids stay on
    // one XCD; x remains fastest, so all col-blocks of one row-tile share L2.
    const int nbx = gridDim.x;
    const int total = nbx * gridDim.y;
    const int lin = blockIdx.y * nbx + blockIdx.x;
    const int qq = total >> 3, rr = total & 7, cc = lin & 7, ss = lin >> 3;
    const int w = (cc < rr ? cc * (qq + 1) : rr * (qq + 1) + (cc - rr) * qq) + ss;
    const int bx = w % nbx, by = w / nbx;
    const int col0 = bx * 128, row0 = by * 128;
    const int l15 = lane & 15, lg = lane >> 4;

    const float* Xf = (const float*)Xv;
    const short* Xb = (const short*)Xv;

    f4v acc[16];
#pragma unroll
    for (int i = 0; i < 16; ++i) acc[i] = (f4v){0.f, 0.f, 0.f, 0.f};

    s8v rxb[2][2];      // bf16 X prefetch regs [set][chunk]
    float4 rxf[2][4];   // fp32 X prefetch regs
    s8v rw[2][2];       // W prefetch regs

    // prologue: tile0 -> LDS buf0, tile1 loads in flight
    GEMM_GLD(0, 0);
    GEMM_GST(0, 0);
    GEMM_GLD(1, 32);
    __syncthreads();

#pragma unroll
    for (int kk = 0; kk < 8; ++kk) {
        const int cur = kk & 1;
        if (kk + 2 < 8) GEMM_GLD(cur, (kk + 2) * 32);   // set cur free: stored last iter
        s8v af[4], bfr[4];
#pragma unroll
        for (int i = 0; i < 4; ++i) af[i]  = *(const s8v*)(Xs[cur] + (wm + i*16 + l15) * 40 + lg * 8);
#pragma unroll
        for (int j = 0; j < 4; ++j) bfr[j] = *(const s8v*)(Ws[cur] + (wn + j*16 + l15) * 40 + lg * 8);
#pragma unroll
        for (int i = 0; i < 4; ++i)
#pragma unroll
            for (int j = 0; j < 4; ++j)
                acc[i*4+j] = __builtin_amdgcn_mfma_f32_16x16x32_bf16(af[i], bfr[j], acc[i*4+j], 0, 0, 0);
        __syncthreads();                                 // all waves done reading buf[cur]
        if (kk + 1 < 8) {
            GEMM_GST(cur ^ 1, cur ^ 1);                  // tile kk+1 -> other buffer
            __syncthreads();                             // buf[cur^1] ready
        }
    }

#pragma unroll
    for (int i = 0; i < 4; ++i) {
#pragma unroll
        for (int r = 0; r < 4; ++r) {
            int gr = row0 + wm + i*16 + lg*4 + r;
            if (gr >= n) continue;
            float sc = SCALE ? rowscale[gr] : 1.0f;
#pragma unroll
            for (int j = 0; j < 4; ++j) {
                int gcv = col0 + wn + j*16 + l15;
                float v = acc[i*4+j][r];
                if (LEAKY) v = (v >= 0.f) ? v : 0.1f * v;
                if (SCALE) v *= sc;
                if (NBUF == 1) {
                    size_t off = (size_t)gr * 256 + gcv;
                    if (RESID) v += bf2f(residb[off]);
                    if (WF32) Yf[off] = v;
                    if (WBF16) Yb[off] = f2bf(v);
                } else {
                    size_t off = (size_t)(gcv >> 8) * bufstride + (size_t)gr * 256 + (gcv & 255);
                    if (WBF16) Yb[off] = f2bf(v);
                }
            }
        }
    }
}

// ---------- MFMA sigmoid attention: O = sum_tiles sigmoid(Q Kt^T) Vt ----------
__global__ __launch_bounds__(256, 2) void attn_mfma(
    const short* __restrict__ Qb, const short* __restrict__ Kb, const short* __restrict__ Vb,
    short* __restrict__ Ob, const int* __restrict__ qs, const int* __restrict__ ks)
{
    __shared__ short Kl[32 * 264];
    __shared__ short Vt[256 * 40];
    __shared__ short Ss[4][16 * 40];
    const int b = blockIdx.x;
    const int q0 = qs[2*b], qc = qs[2*b+1];
    const int k0 = ks[2*b], kc = ks[2*b+1];
    if ((int)blockIdx.y * 64 >= qc) return;           // block-uniform exit
    const int t = threadIdx.x, lane = t & 63, wave = t >> 6;
    const int l15 = lane & 15, lg = lane >> 4;
    const int qtile = blockIdx.y * 4 + wave;
    const bool valid = qtile * 16 < qc;

    s8v qf[8];
    {
        int qr = qtile * 16 + l15;
        if (qr >= qc) qr = qc - 1;                     // clamp (results discarded)
        const short* qp = Qb + (size_t)(q0 + qr) * 256 + lg * 8;
#pragma unroll
        for (int s = 0; s < 8; ++s) qf[s] = *(const s8v*)(qp + s * 32);
    }
    f4v o[16];
#pragma unroll
    for (int i = 0; i < 16; ++i) o[i] = (f4v){0.f, 0.f, 0.f, 0.f};

    const int nkt = (kc + 31) >> 5;
    for (int kt = 0; kt < nkt; ++kt) {
        __syncthreads();
#pragma unroll
        for (int i = 0; i < 4; ++i) {
            int c = t + i * 256;                       // 0..1023
            int key = c >> 5, d0 = (c & 31) * 8;
            int gk = kt * 32 + key;
            s8v kv = (s8v){0,0,0,0,0,0,0,0}, vv = kv;
            if (gk < kc) {
                kv = *(const s8v*)(Kb + (size_t)(k0 + gk) * 256 + d0);
                vv = *(const s8v*)(Vb + (size_t)(k0 + gk) * 256 + d0);
            }
            *(s8v*)(Kl + key * 264 + d0) = kv;
#pragma unroll
            for (int j = 0; j < 8; ++j) {
                int d = d0 + j;
                int kcol = key ^ (((d >> 3) & 3) << 3);   // XOR-8 swizzle
                Vt[d * 40 + kcol] = vv[j];
            }
        }
        __syncthreads();
        if (valid) {
#pragma unroll
            for (int nt = 0; nt < 2; ++nt) {
                f4v s = (f4v){0.f, 0.f, 0.f, 0.f};
#pragma unroll
                for (int ss = 0; ss < 8; ++ss) {
                    s8v kb = *(const s8v*)(Kl + (nt*16 + l15) * 264 + ss * 32 + lg * 8);
                    s = __builtin_amdgcn_mfma_f32_16x16x32_bf16(qf[ss], kb, s, 0, 0, 0);
                }
#pragma unroll
                for (int r = 0; r < 4; ++r) {
                    float sv = 1.0f / (1.0f + __expf(-s[r]));
                    Ss[wave][(lg*4 + r) * 40 + nt*16 + l15] = f2bf(sv);
                }
            }
            __builtin_amdgcn_s_waitcnt(0xc07f);        // lgkmcnt(0): S write->read
            s8v sa = *(const s8v*)(&Ss[wave][0] + l15 * 40 + lg * 8);
#pragma unroll
            for (int nt = 0; nt < 16; ++nt) {
                int rowb = nt * 16 + l15;
                s8v vb = *(const s8v*)(Vt + rowb * 40 + (lg ^ ((rowb >> 3) & 3)) * 8);
                o[nt] = __builtin_amdgcn_mfma_f32_16x16x32_bf16(sa, vb, o[nt], 0, 0, 0);
            }
        }
    }
    if (valid) {
#pragma unroll
        for (int nt = 0; nt < 16; ++nt) {
#pragma unroll
            for (int r = 0; r < 4; ++r) {
                int qr = qtile * 16 + lg * 4 + r;
                if (qr < qc) Ob[(size_t)(q0 + qr) * 256 + nt*16 + l15] = f2bf(o[nt][r]);
            }
        }
    }
}

extern "C" void kernel_launch(void* const* d_in, const int* in_sizes, int n_in,
                              void* d_out, int out_size, void* d_ws, size_t ws_size,
                              hipStream_t stream)
{
    const float* fatoms = (const float*)d_in[0];
    const float* fres   = (const float*)d_in[1];
    const int* lig_raw  = (const int*)d_in[12];
    const int* res_raw  = (const int*)d_in[13];
    const int nA = in_sizes[0] / DD;
    const int nR = in_sizes[1] / DD;
    (void)n_in; (void)out_size; (void)ws_size;

    char* p = (char*)d_ws;
    auto carve = [&](size_t bytes) -> void* {
        void* r = (void*)p;
        p += (bytes + 255) & ~(size_t)255;
        return r;
    };
    short* Ab = (short*)carve((size_t)nA * DD * 2);   // bf16 state (fp32 state removed)
    short* Rb = (short*)carve((size_t)nR * DD * 2);
    short* AQ = (short*)carve((size_t)nA * DD * 2);   // AQ,AK,AV contiguous (QKV decode)
    short* AK = (short*)carve((size_t)nA * DD * 2);
    short* AV = (short*)carve((size_t)nA * DD * 2);
    short* RQ = (short*)carve((size_t)nR * DD * 2);   // RQ,RK,RV contiguous
    short* RK = (short*)carve((size_t)nR * DD * 2);
    short* RV = (short*)carve((size_t)nR * DD * 2);
    float* sA = (float*)carve((size_t)nA * 4);
    float* sR = (float*)carve((size_t)nR * 4);
    int* ligN = (int*)carve(NCPLX * 2 * 4);
    int* resN = (int*)carve(NCPLX * 2 * 4);
    short* Wt = (short*)carve((size_t)10 * 65536 * 2); // 10 transposed bf16 weights
    (void)AK; (void)AV; (void)RK; (void)RV;

    const short* WqkvL = Wt + 0*65536;   // QKl,WKl,WVl contiguous (N=768)
    const short* WOlT  = Wt + 3*65536;
    const short* WqkvR = Wt + 4*65536;   // QKr,WKr,WVr contiguous
    const short* WOrT  = Wt + 7*65536;
    const short* WligT = Wt + 8*65536;
    const short* WresT = Wt + 9*65536;

    float* out = (float*)d_out;
    const dim3 blk(256);
    const int gA = (nA + 127) / 128, gR = (nR + 127) / 128;
    const size_t bsA = (size_t)nA * DD, bsR = (size_t)nR * DD;

    conv_scope<<<1, NCPLX, 0, stream>>>(lig_raw, res_raw, nA, nR, ligN, resN);
    scales_k<<<NCPLX, 256, 0, stream>>>(ligN, resN, sA, sR);
    wtrans<<<dim3(10, 64), blk, 0, stream>>>(
        (const float*)d_in[4], (const float*)d_in[5], (const float*)d_in[6], (const float*)d_in[7],
        (const float*)d_in[8], (const float*)d_in[9], (const float*)d_in[10], (const float*)d_in[11],
        (const float*)d_in[2], (const float*)d_in[3], Wt);

    // input transforms: bf16 state only
    gemm_mfma<true,true,false,false,false,true,1><<<dim3(2, gA), blk, 0, stream>>>(
        fatoms, WligT, nullptr, Ab, 0, nullptr, nullptr, nA);
    gemm_mfma<true,true,false,false,false,true,1><<<dim3(2, gR), blk, 0, stream>>>(
        fres, WresT, nullptr, Rb, 0, nullptr, nullptr, nR);

    for (int it = 0; it < NITER; ++it) {
        // fused QKV projections: one N=768 GEMM per side
        gemm_mfma<false,false,false,false,false,true,3><<<dim3(6, gA), blk, 0, stream>>>(
            Ab, WqkvL, nullptr, AQ, bsA, nullptr, nullptr, nA);
        gemm_mfma<false,false,false,false,false,true,3><<<dim3(6, gR), blk, 0, stream>>>(
            Rb, WqkvR, nullptr, RQ, bsR, nullptr, nullptr, nR);

        attn_mfma<<<dim3(NCPLX, 1), blk, 0, stream>>>(AQ, RK, RV, AQ, ligN, resN);
        attn_mfma<<<dim3(NCPLX, 8), blk, 0, stream>>>(RQ, AK, AV, RQ, resN, ligN);

        if (it < NITER - 1) {
            // state update in bf16: read resid Ab/Rb, write Ab/Rb (same-thread RMW, safe)
            gemm_mfma<false,true,true,true,false,true,1><<<dim3(2, gA), blk, 0, stream>>>(
                AQ, WOlT, nullptr, Ab, 0, Ab, sA, nA);
            gemm_mfma<false,true,true,true,false,true,1><<<dim3(2, gR), blk, 0, stream>>>(
                RQ, WOrT, nullptr, Rb, 0, Rb, sR, nR);
        } else {
            gemm_mfma<false,true,true,true,true,false,1><<<dim3(2, gA), blk, 0, stream>>>(
                AQ, WOlT, out, nullptr, 0, Ab, sA, nA);
            gemm_mfma<false,true,true,true,true,false,1><<<dim3(2, gR), blk, 0, stream>>>(
                RQ, WOrT, out + bsA, nullptr, 0, Rb, sR, nR);
        }
    }
}